// Round 5
// baseline (323.692 us; speedup 1.0000x reference)
//
#include <hip/hip_runtime.h>
#include <stdint.h>

#define BTOT 32768
#define NIMG 16      // images per conv block
#define KF   416     // padded feature dim (400 real)

typedef __attribute__((ext_vector_type(8))) short short8;
typedef __attribute__((ext_vector_type(4))) float floatx4;
typedef __attribute__((ext_vector_type(4))) unsigned int uintx4;

__device__ __forceinline__ unsigned short f2bf(float x) {
    union { float f; unsigned int u; } v; v.f = x;
    unsigned int r = v.u + 0x7fffu + ((v.u >> 16) & 1u);  // RNE
    return (unsigned short)(r >> 16);
}
__device__ __forceinline__ unsigned int pk2(float a, float b) {
    return (unsigned int)f2bf(a) | ((unsigned int)f2bf(b) << 16);
}

// a-operand from 3 row dwords; cx=0: taps = halves 0..4 (slots 5..7 garbage, zero weight)
#define MK0(d0, d1, d2) __builtin_bit_cast(short8, (uintx4){(d0), (d1), (d2), (d0)})
// cx=1: taps = halves 1..5
#define MK1(d0, d1, d2) __builtin_bit_cast(short8, (uintx4){ \
    __builtin_amdgcn_alignbit((d1), (d0), 16), \
    __builtin_amdgcn_alignbit((d2), (d1), 16), \
    (d2) >> 16, (d0)})

// ---------------- conv(5x5,3->16) + bias + relu + 2x2 maxpool via MFMA implicit GEMM ----------
// M = 16 IMAGES, tile = (quad, corner). Lane&15 = image (A row) / co (B col, D col).
// LDS: FLAT 294-dword-per-image staging (rounds 1-3 proven, NO unwritten holes: every read
// [o, o+69] is within the written [0,293]).  Round-4 bug was the stride-99 layout's write-gap
// at dword 98 read by the phantom chunk -> NaN poisoning; eliminated structurally here.
// K chunks (ci,row), o = ci*98 + row*7; (i,q) table keeps 2-even+2-odd offsets per MFMA read
// (il*294 mod 32 = il*6 -> each lane-group covers all 16 even banks once).
__global__ __launch_bounds__(256) void conv_pool_kernel(
    const float* __restrict__ fm, const float* __restrict__ cw,
    const float* __restrict__ cb, unsigned short* __restrict__ feat,
    const float* __restrict__ lw, unsigned short* __restrict__ Wb)
{
    // -------- folded prep_w path (blocks 2048..2255) --------
    if (blockIdx.x >= BTOT / NIMG) {
        int c = (blockIdx.x - BTOT / NIMG) * 256 + threadIdx.x;   // one 8-element chunk
        if (c < 1024 * 52) {
            int n = c / 52;
            int kc = (c - n * 52) * 8;
            unsigned short v[8];
            #pragma unroll
            for (int j = 0; j < 8; ++j) {
                int k = kc + j;
                float x = (n < 1000 && k < 400) ? lw[n * 400 + k] : 0.f;
                v[j] = f2bf(x);
            }
            *(uint4*)(Wb + (size_t)n * KF + kc) = *(uint4*)v;
        }
        return;
    }

    __shared__ __align__(16) unsigned int s_img[NIMG * 294];   // flat bf16 images, 18816 B

    const int tid  = threadIdx.x;
    const int b0   = blockIdx.x * NIMG;
    const int lane = tid & 63;

    // stage 16 images fp32 -> bf16, layout-preserving flat copy, b128 LDS writes (proven r1-r3)
    const float4* in4 = (const float4*)(fm + (size_t)b0 * 588);
    for (int idx = tid; idx < NIMG * 147 / 2; idx += 256) {
        float4 v0 = in4[2 * idx], v1 = in4[2 * idx + 1];
        uint4 u;
        u.x = pk2(v0.x, v0.y);
        u.y = pk2(v0.z, v0.w);
        u.z = pk2(v1.x, v1.y);
        u.w = pk2(v1.z, v1.w);
        *(uint4*)&s_img[idx * 4] = u;
    }
    // zero-pad feat[b][400..416) for all 16 images
    {
        int img = tid >> 4, k = tid & 15;
        feat[(size_t)(b0 + img) * KF + 400 + k] = 0;
    }

    const int il = lane & 15;    // A: image; B/D: co
    const int q  = lane >> 4;    // k-chunk group (A/B), quad-in-D (store)

    // chunk offsets o = ci*98 + row*7 per (MFMA i, q); (3,3) = phantom (dup of o=7, zero wts)
    const int o0 = q == 0 ? 0   : q == 1 ? 7   : q == 2 ? 14  : 21;
    const int o1 = q == 0 ? 28  : q == 1 ? 105 : q == 2 ? 98  : 119;
    const int o2 = q == 0 ? 112 : q == 1 ? 203 : q == 2 ? 126 : 217;
    const int o3 = q == 0 ? 196 : q == 1 ? 210 : q == 2 ? 224 : 7;

    auto loadw = [&](int o, bool ph) -> short8 {
        short8 w = {};
        if (!ph) {
            int ci  = o >= 196 ? 2 : (o >= 98 ? 1 : 0);
            int row = (o - ci * 98) / 7;
            #pragma unroll
            for (int j = 0; j < 5; ++j)
                w[j] = (short)f2bf(cw[il * 75 + ci * 25 + row * 5 + j]);
        }
        return w;
    };
    const short8 bw0 = loadw(o0, false);
    const short8 bw1 = loadw(o1, false);
    const short8 bw2 = loadw(o2, false);
    const short8 bw3 = loadw(o3, q == 3);
    const float bias = cb[il];

    __syncthreads();

    const unsigned int* ap0 = s_img + il * 294 + o0;
    const unsigned int* ap1 = s_img + il * 294 + o1;
    const unsigned int* ap2 = s_img + il * 294 + o2;
    const unsigned int* ap3 = s_img + il * 294 + o3;

    const int wave = tid >> 6;
    int p = wave, qy = 0, qx = wave;     // wave w handles quads w, w+4, ... (7/6/6/6)
    while (p < 25) {
        const int u = qy * 14 + qx;      // dwords: conv rows 2qy(+cy+kh), col dword qx

        unsigned int d00 = ap0[u], d01 = ap0[u + 1], d02 = ap0[u + 2];
        unsigned int d10 = ap1[u], d11 = ap1[u + 1], d12 = ap1[u + 2];
        unsigned int d20 = ap2[u], d21 = ap2[u + 1], d22 = ap2[u + 2];
        unsigned int d30 = ap3[u], d31 = ap3[u + 1], d32 = ap3[u + 2];
        unsigned int e00 = ap0[u + 7], e01 = ap0[u + 8], e02 = ap0[u + 9];
        unsigned int e10 = ap1[u + 7], e11 = ap1[u + 8], e12 = ap1[u + 9];
        unsigned int e20 = ap2[u + 7], e21 = ap2[u + 8], e22 = ap2[u + 9];
        unsigned int e30 = ap3[u + 7], e31 = ap3[u + 8], e32 = ap3[u + 9];

        floatx4 z = {0.f, 0.f, 0.f, 0.f};
        floatx4 A00 = z, A01 = z, A10 = z, A11 = z;   // [cy][cx]

        A00 = __builtin_amdgcn_mfma_f32_16x16x32_bf16(MK0(d00, d01, d02), bw0, A00, 0, 0, 0);
        A00 = __builtin_amdgcn_mfma_f32_16x16x32_bf16(MK0(d10, d11, d12), bw1, A00, 0, 0, 0);
        A00 = __builtin_amdgcn_mfma_f32_16x16x32_bf16(MK0(d20, d21, d22), bw2, A00, 0, 0, 0);
        A00 = __builtin_amdgcn_mfma_f32_16x16x32_bf16(MK0(d30, d31, d32), bw3, A00, 0, 0, 0);

        A01 = __builtin_amdgcn_mfma_f32_16x16x32_bf16(MK1(d00, d01, d02), bw0, A01, 0, 0, 0);
        A01 = __builtin_amdgcn_mfma_f32_16x16x32_bf16(MK1(d10, d11, d12), bw1, A01, 0, 0, 0);
        A01 = __builtin_amdgcn_mfma_f32_16x16x32_bf16(MK1(d20, d21, d22), bw2, A01, 0, 0, 0);
        A01 = __builtin_amdgcn_mfma_f32_16x16x32_bf16(MK1(d30, d31, d32), bw3, A01, 0, 0, 0);

        A10 = __builtin_amdgcn_mfma_f32_16x16x32_bf16(MK0(e00, e01, e02), bw0, A10, 0, 0, 0);
        A10 = __builtin_amdgcn_mfma_f32_16x16x32_bf16(MK0(e10, e11, e12), bw1, A10, 0, 0, 0);
        A10 = __builtin_amdgcn_mfma_f32_16x16x32_bf16(MK0(e20, e21, e22), bw2, A10, 0, 0, 0);
        A10 = __builtin_amdgcn_mfma_f32_16x16x32_bf16(MK0(e30, e31, e32), bw3, A10, 0, 0, 0);

        A11 = __builtin_amdgcn_mfma_f32_16x16x32_bf16(MK1(e00, e01, e02), bw0, A11, 0, 0, 0);
        A11 = __builtin_amdgcn_mfma_f32_16x16x32_bf16(MK1(e10, e11, e12), bw1, A11, 0, 0, 0);
        A11 = __builtin_amdgcn_mfma_f32_16x16x32_bf16(MK1(e20, e21, e22), bw2, A11, 0, 0, 0);
        A11 = __builtin_amdgcn_mfma_f32_16x16x32_bf16(MK1(e30, e31, e32), bw3, A11, 0, 0, 0);

        // 2x2 pool across the 4 same-layout corner accs + bias + relu + store
        // D: col = lane&15 = co, row = q*4 + rr = image (m89/m91, GEMM-proven)
        unsigned short* fq = feat + (size_t)(b0 + 4 * q) * KF + il * 25 + p;
        #pragma unroll
        for (int rr = 0; rr < 4; ++rr) {
            float m = fmaxf(fmaxf(A00[rr], A01[rr]), fmaxf(A10[rr], A11[rr])) + bias;
            fq[(size_t)rr * KF] = f2bf(fmaxf(m, 0.f));
        }

        p += 4; qx += 4;
        if (qx >= 5) { qx -= 5; ++qy; }
    }
}

// ---------------- GEMM: out[32768][1000] = F[32768][416] @ Wb[1024][416]^T + lin_b ----------------
// m97 pattern: global_load_lds width=16 staging (dest = wave-uniform base + lane*16).
__global__ __launch_bounds__(256) void gemm_kernel(
    const unsigned short* __restrict__ F, const unsigned short* __restrict__ Wb,
    const float* __restrict__ lb, float* __restrict__ out)
{
    __shared__ __align__(16) unsigned short At[128 * 32];
    __shared__ __align__(16) unsigned short Bt[128 * 32];

    const int tid = threadIdx.x;
    const int bm = blockIdx.x >> 3;
    const int bn = blockIdx.x & 7;
    const int m0 = bm * 128;
    const int n0 = bn * 128;

    const int w = tid >> 6;
    const int lane = tid & 63;
    const int wm = w & 1, wn = w >> 1;     // 2x2 wave grid, each wave 64x64
    const int lq = lane >> 4, ln = lane & 15;

    floatx4 zero = {0.f, 0.f, 0.f, 0.f};
    floatx4 acc[4][4];
    #pragma unroll
    for (int i = 0; i < 4; ++i)
        #pragma unroll
        for (int j = 0; j < 4; ++j) acc[i][j] = zero;

    // staging: wave w covers rows [w*16, w*16+16) (+64 for t=1); lane L -> row w*16+(L>>2), chunk L&3
    const int srow = w * 16 + (lane >> 2);
    const int skc = (lane & 3) * 8;
    const unsigned short* gA = F + (size_t)(m0 + srow) * KF + skc;
    const unsigned short* gB = Wb + (size_t)(n0 + srow) * KF + skc;

    for (int kb = 0; kb < KF; kb += 32) {
        #pragma unroll
        for (int t = 0; t < 2; ++t) {
            __builtin_amdgcn_global_load_lds(
                (const __attribute__((address_space(1))) void*)(gA + (size_t)(t * 64) * KF + kb),
                (__attribute__((address_space(3))) void*)&At[(w * 16 + t * 64) * 32],
                16, 0, 0);
            __builtin_amdgcn_global_load_lds(
                (const __attribute__((address_space(1))) void*)(gB + (size_t)(t * 64) * KF + kb),
                (__attribute__((address_space(3))) void*)&Bt[(w * 16 + t * 64) * 32],
                16, 0, 0);
        }
        __syncthreads();
        short8 af[4], bf[4];
        #pragma unroll
        for (int i = 0; i < 4; ++i)
            af[i] = *(const short8*)&At[(wm * 64 + i * 16 + ln) * 32 + lq * 8];
        #pragma unroll
        for (int j = 0; j < 4; ++j)
            bf[j] = *(const short8*)&Bt[(wn * 64 + j * 16 + ln) * 32 + lq * 8];
        #pragma unroll
        for (int i = 0; i < 4; ++i)
            #pragma unroll
            for (int j = 0; j < 4; ++j)
                acc[i][j] = __builtin_amdgcn_mfma_f32_16x16x32_bf16(af[i], bf[j], acc[i][j], 0, 0, 0);
        __syncthreads();
    }

    #pragma unroll
    for (int j = 0; j < 4; ++j) {
        int n = n0 + wn * 64 + j * 16 + ln;
        if (n >= 1000) continue;           // padded N region
        float bias = lb[n];
        #pragma unroll
        for (int i = 0; i < 4; ++i) {
            int mb = m0 + wm * 64 + i * 16 + lq * 4;   // C/D: col=lane&15, row=quad*4+reg (m89/m91)
            #pragma unroll
            for (int rr = 0; rr < 4; ++rr)
                out[(size_t)(mb + rr) * 1000 + n] = acc[i][j][rr] + bias;
        }
    }
}

extern "C" void kernel_launch(void* const* d_in, const int* in_sizes, int n_in,
                              void* d_out, int out_size, void* d_ws, size_t ws_size,
                              hipStream_t stream)
{
    const float* fm = (const float*)d_in[0];   // (32768,3,14,14)
    const float* cw = (const float*)d_in[1];   // (16,3,5,5)
    const float* cb = (const float*)d_in[2];   // (16,)
    const float* lw = (const float*)d_in[3];   // (1000,400)
    const float* lb = (const float*)d_in[4];   // (1000,)
    float* out = (float*)d_out;                // (32768,1000) fp32

    unsigned short* feat = (unsigned short*)d_ws;                        // [32768][416] bf16
    unsigned short* Wb   = (unsigned short*)d_ws + (size_t)BTOT * KF;    // [1024][416] bf16

    // conv blocks [0,2048) + folded prep_w blocks [2048,2256)
    conv_pool_kernel<<<BTOT / NIMG + 208, 256, 0, stream>>>(fm, cw, cb, feat, lw, Wb);
    gemm_kernel<<<2048, 256, 0, stream>>>(feat, Wb, lb, out);
}